// Round 6
// baseline (12494.494 us; speedup 1.0000x reference)
//
#include <hip/hip_runtime.h>
#include <hip/hip_bf16.h>
#include <cstring>

// ---- problem constants ----
#define NB 8
#define NT 64
#define NNODE 24
#define ND 6
#define NH 128
#define NR 64
#define NNE 4
#define NEDGE 552                  // NNODE*(NNODE-1)
#define NSEQ (NB*NEDGE)            // 4416
#define ROWS1 (NB*NNODE*NT)        // 12288
#define ROWS2 (NB*NEDGE*NT)        // 282624
#define PRIOR_SZ (NB*NT*NEDGE*NNE) // 1130496

typedef __hip_bfloat16 bf16;
typedef unsigned short u16;
typedef unsigned int u32;

__device__ __forceinline__ float eluf(float x){ return x > 0.f ? x : expm1f(x); }
__device__ __forceinline__ float b2f(bf16 v){ return __bfloat162float(v); }

// ---------------- diagnostics (fp32 output) ----------------
__global__ void k_fill(float* out, int n, float pat){
  const int i = blockIdx.x*256 + threadIdx.x;
  if(i < n) out[i] = pat;
}
// m1b1 is full(0.1, fp32) -> first word must be 0x3DCCCCCD. Otherwise flood ~3000.
__global__ void k_sentinel(const u32* probe, float* out, int n){
  if(probe[0] == 0x3DCCCCCDu) return;
  const int i = blockIdx.x*256 + threadIdx.x;
  if(i < n) out[i] = 3000.0f;
}
__global__ void k_zero(float* aux){
  for(int i = threadIdx.x; i < 1024; i += 256) aux[i] = 0.f;
}

// ---------------- MLP1: (B,N,T,D)->H->H, pre-BN out + channel sums ----------------
__global__ __launch_bounds__(128) void k_mlp1(
    const float* inp, const float* w1, const float* b1,
    const float* w2, const float* b2,
    float* X1, float* sum, float* sq)
{
  const int j = threadIdx.x;
  __shared__ float xin[ND];
  __shared__ float h1[NH];
  const float b1j = b1[j], b2j = b2[j];
  float wcol[ND];
  for(int d = 0; d < ND; d++) wcol[d] = w1[d*NH + j];
  float accS = 0.f, accQ = 0.f;
  const int row0 = blockIdx.x*16;
  for(int r = 0; r < 16; r++){
    const int row = row0 + r;
    const int b = row/(NNODE*NT); const int rem = row - b*(NNODE*NT);
    const int n = rem/NT; const int t = rem - n*NT;
    if(j < ND) xin[j] = inp[((b*NT + t)*NNODE + n)*ND + j];
    __syncthreads();
    float a = b1j;
    for(int d = 0; d < ND; d++) a += xin[d]*wcol[d];
    h1[j] = eluf(a);
    __syncthreads();
    float a2 = b2j;
    for(int k = 0; k < NH; k++) a2 += h1[k]*w2[k*NH + j];
    const float h2 = eluf(a2);
    X1[row*NH + j] = h2; accS += h2; accQ += h2*h2;
    __syncthreads();
  }
  atomicAdd(&sum[j], accS); atomicAdd(&sq[j], accQ);
}

// ---------------- BN params ----------------
__global__ void k_bn(const float* sum, const float* sq,
                     const float* g, const float* be,
                     float inv_cnt, float* sc, float* sh)
{
  const int j = threadIdx.x;
  const float m = sum[j]*inv_cnt;
  const float v = fmaxf(sq[j]*inv_cnt - m*m, 0.f);
  const float s = g[j]*rsqrtf(v + 1e-5f);
  sc[j] = s; sh[j] = be[j] - m*s;
}

// ---------------- edge MLPs (MLP2: KIN=256, MLP4: KIN=384) ----------------
// For KIN=384 (MLP4) Eo may equal Ein: each block stages its own 8 rows into
// LDS (then barrier) before overwriting those same rows. Blocks own disjoint rows.
template<int KIN>
__global__ __launch_bounds__(128) void k_mlp_edge(
  const float* Xn, const float* scN, const float* shN,
  const bf16* Ein, const float* scE, const float* shE,
  const float* w1, const float* b1, const float* w2, const float* b2,
  bf16* Eo, float* sum, float* sq)
{
  const int j = threadIdx.x;
  constexpr int CH = 8;
  __shared__ float xin[CH][KIN];
  __shared__ float h1s[CH][NH];
  const int g0 = blockIdx.x*CH;
  const float sN = scN[j], tN = shN[j];
  float sE = 0.f, tE = 0.f;
  if constexpr(KIN == 3*NH){ sE = scE[j]; tE = shE[j]; }
  for(int r = 0; r < CH; r++){
    const int row = g0 + r;
    const int b = row/(NEDGE*NT); const int rem = row - b*(NEDGE*NT);
    const int e = rem/NT; const int t = rem - e*NT;
    const int snd = e/23, r0 = e - snd*23;
    const int rcv = r0 + (r0 >= snd ? 1 : 0);
    xin[r][j]      = Xn[((b*NNODE + snd)*NT + t)*NH + j]*sN + tN;
    xin[r][NH + j] = Xn[((b*NNODE + rcv)*NT + t)*NH + j]*sN + tN;
    if constexpr(KIN == 3*NH)
      xin[r][2*NH + j] = b2f(Ein[(size_t)row*NH + j])*sE + tE;
  }
  __syncthreads();
  float acc[CH];
  for(int r = 0; r < CH; r++) acc[r] = b1[j];
  for(int k = 0; k < KIN; k++){
    const float wv = w1[k*NH + j];
    for(int r = 0; r < CH; r++) acc[r] += xin[r][k]*wv;
  }
  for(int r = 0; r < CH; r++) h1s[r][j] = eluf(acc[r]);
  __syncthreads();
  for(int r = 0; r < CH; r++) acc[r] = b2[j];
  for(int k = 0; k < NH; k++){
    const float wv = w2[k*NH + j];
    for(int r = 0; r < CH; r++) acc[r] += h1s[r][k]*wv;
  }
  float accS = 0.f, accQ = 0.f;
  for(int r = 0; r < CH; r++){
    const float h2 = eluf(acc[r]);
    Eo[(size_t)(g0 + r)*NH + j] = __float2bfloat16(h2);
    accS += h2; accQ += h2*h2;
  }
  atomicAdd(&sum[j], accS); atomicAdd(&sq[j], accQ);
}

// ---------------- agg (mean over incoming edges, BN-affine commutes) + MLP3 ----
__global__ __launch_bounds__(128) void k_mlp3(
    const bf16* Ein, const float* scE, const float* shE,
    const float* w1, const float* b1, const float* w2, const float* b2,
    float* X3, float* sum, float* sq)
{
  const int j = threadIdx.x;
  __shared__ float xin[NH];
  __shared__ float h1[NH];
  const float sE = scE[j], tE = shE[j];
  float accS = 0.f, accQ = 0.f;
  const int row0 = blockIdx.x*16;
  for(int r = 0; r < 16; r++){
    const int row = row0 + r;
    const int b = row/(NNODE*NT); const int rem = row - b*(NNODE*NT);
    const int n = rem/NT; const int t = rem - n*NT;
    float s = 0.f;
    for(int i = 0; i < NNODE; i++){
      if(i == n) continue;
      const int e = i*23 + (n < i ? n : n - 1);   // edge i -> n
      s += b2f(Ein[((size_t)(b*NEDGE + e)*NT + t)*NH + j]);
    }
    xin[j] = sE*s*(1.f/23.f) + tE;
    __syncthreads();
    float a = b1[j];
    for(int k = 0; k < NH; k++) a += xin[k]*w1[k*NH + j];
    h1[j] = eluf(a);
    __syncthreads();
    float a2 = b2[j];
    for(int k = 0; k < NH; k++) a2 += h1[k]*w2[k*NH + j];
    const float h2 = eluf(a2);
    X3[row*NH + j] = h2; accS += h2; accQ += h2*h2;
    __syncthreads();
  }
  atomicAdd(&sum[j], accS); atomicAdd(&sq[j], accQ);
}

// ---------------- forward GRU, wave-per-sequence, fused prior+enc-partial ------
__global__ __launch_bounds__(256) void k_gru_fwd(
  const bf16* E4, const float* sc4, const float* sh4,
  const float* wih, const float* whh, const float* bih, const float* bhh,
  const float* pw, const float* pb, const float* ew,
  float* encp, float* outP, float* hT)
{
  __shared__ float xsh[4][NH];
  __shared__ float hsh[4][NR];
  const int tid = threadIdx.x;
  const int w = tid >> 6, c = tid & 63;          // wave w handles one sequence
  const int s = blockIdx.x*4 + w;
  const int sb = s/NEDGE, se = s - sb*NEDGE;
  const float bxr = bih[c], bxz = bih[64+c], bxn = bih[128+c];
  const float bhr = bhh[c], bhz = bhh[64+c], bhn = bhh[128+c];
  float pwl[NNE], ewl[NNE];
  for(int l = 0; l < NNE; l++){ pwl[l] = pw[c*NNE + l]; ewl[l] = ew[c*NNE + l]; }
  hsh[w][c] = 0.f;
  float hprev = 0.f;
  __syncthreads();
  for(int tt = 0; tt < NT; tt++){
    const size_t xb = ((size_t)s*NT + tt)*NH;
    xsh[w][c]      = b2f(E4[xb + c])*sc4[c] + sh4[c];
    xsh[w][c + 64] = b2f(E4[xb + c + 64])*sc4[c + 64] + sh4[c + 64];
    __syncthreads();
    float xr = bxr, xz = bxz, xn = bxn;
    for(int k = 0; k < NH; k++){
      const float xv = xsh[w][k];
      xr += xv*wih[c*NH + k];
      xz += xv*wih[(64 + c)*NH + k];
      xn += xv*wih[(128 + c)*NH + k];
    }
    float hr = bhr, hz = bhz, hn = bhn;
    for(int k = 0; k < NR; k++){
      const float hv = hsh[w][k];
      hr += hv*whh[c*NR + k];
      hz += hv*whh[(64 + c)*NR + k];
      hn += hv*whh[(128 + c)*NR + k];
    }
    const float rg = 1.f/(1.f + expf(-(xr + hr)));
    const float zg = 1.f/(1.f + expf(-(xz + hz)));
    const float ng = tanhf(xn + rg*hn);
    const float hnew = (1.f - zg)*ng + zg*hprev;
    __syncthreads();
    hsh[w][c] = hnew; hprev = hnew;
    float v[8];
    for(int l = 0; l < NNE; l++){ v[l] = hnew*pwl[l]; v[4 + l] = hnew*ewl[l]; }
    for(int m = 1; m < 64; m <<= 1)
      for(int q = 0; q < 8; q++) v[q] += __shfl_xor(v[q], m);
    const size_t ob = ((size_t)(sb*NT + tt)*NEDGE + se)*NNE;
    if(c < NNE) outP[ob + c] = v[c] + pb[c];
    else if(c < 2*NNE) encp[((size_t)s*NT + tt)*NNE + (c - NNE)] = v[c];
    __syncthreads();
  }
  hT[(size_t)s*NR + c] = hprev;
}

// ---------------- reverse GRU, fused enc projection ----------------
__global__ __launch_bounds__(256) void k_gru_rev(
  const bf16* E4, const float* sc4, const float* sh4,
  const float* wih, const float* whh, const float* bih, const float* bhh,
  const float* ew, const float* eb,
  const float* encp, float* outE)
{
  __shared__ float xsh[4][NH];
  __shared__ float hsh[4][NR];
  const int tid = threadIdx.x;
  const int w = tid >> 6, c = tid & 63;
  const int s = blockIdx.x*4 + w;
  const int sb = s/NEDGE, se = s - sb*NEDGE;
  const float bxr = bih[c], bxz = bih[64+c], bxn = bih[128+c];
  const float bhr = bhh[c], bhz = bhh[64+c], bhn = bhh[128+c];
  float ewl[NNE];
  for(int l = 0; l < NNE; l++) ewl[l] = ew[(NR + c)*NNE + l];
  hsh[w][c] = 0.f;
  float hprev = 0.f;
  __syncthreads();
  for(int i = 0; i < NT; i++){
    const int tt = NT - 1 - i;
    const size_t xb = ((size_t)s*NT + tt)*NH;
    xsh[w][c]      = b2f(E4[xb + c])*sc4[c] + sh4[c];
    xsh[w][c + 64] = b2f(E4[xb + c + 64])*sc4[c + 64] + sh4[c + 64];
    __syncthreads();
    float xr = bxr, xz = bxz, xn = bxn;
    for(int k = 0; k < NH; k++){
      const float xv = xsh[w][k];
      xr += xv*wih[c*NH + k];
      xz += xv*wih[(64 + c)*NH + k];
      xn += xv*wih[(128 + c)*NH + k];
    }
    float hr = bhr, hz = bhz, hn = bhn;
    for(int k = 0; k < NR; k++){
      const float hv = hsh[w][k];
      hr += hv*whh[c*NR + k];
      hz += hv*whh[(64 + c)*NR + k];
      hn += hv*whh[(128 + c)*NR + k];
    }
    const float rg = 1.f/(1.f + expf(-(xr + hr)));
    const float zg = 1.f/(1.f + expf(-(xz + hz)));
    const float ng = tanhf(xn + rg*hn);
    const float hnew = (1.f - zg)*ng + zg*hprev;
    __syncthreads();
    hsh[w][c] = hnew; hprev = hnew;
    float v[NNE];
    for(int l = 0; l < NNE; l++) v[l] = hnew*ewl[l];
    for(int m = 1; m < 64; m <<= 1)
      for(int q = 0; q < NNE; q++) v[q] += __shfl_xor(v[q], m);
    if(c < NNE){
      const size_t ob = ((size_t)(sb*NT + tt)*NEDGE + se)*NNE;
      outE[ob + c] = v[c] + encp[((size_t)s*NT + tt)*NNE + c] + eb[c];
    }
    __syncthreads();
  }
}

extern "C" void kernel_launch(void* const* d_in, const int* in_sizes, int n_in,
                              void* d_out, int out_size, void* d_ws, size_t ws_size,
                              hipStream_t stream)
{
  const size_t NEED = 83181568ull;
  if(ws_size < NEED){
    k_fill<<<(out_size + 255)/256, 256, 0, stream>>>((float*)d_out, out_size, 3584.0f);
    return;
  }
  const float* inp  = (const float*)d_in[0];
  const float* m1w1 = (const float*)d_in[1];  const float* m1b1 = (const float*)d_in[2];
  const float* m1w2 = (const float*)d_in[3];  const float* m1b2 = (const float*)d_in[4];
  const float* m1g  = (const float*)d_in[5];  const float* m1be = (const float*)d_in[6];
  const float* m2w1 = (const float*)d_in[7];  const float* m2b1 = (const float*)d_in[8];
  const float* m2w2 = (const float*)d_in[9];  const float* m2b2 = (const float*)d_in[10];
  const float* m2g  = (const float*)d_in[11]; const float* m2be = (const float*)d_in[12];
  const float* m3w1 = (const float*)d_in[13]; const float* m3b1 = (const float*)d_in[14];
  const float* m3w2 = (const float*)d_in[15]; const float* m3b2 = (const float*)d_in[16];
  const float* m3g  = (const float*)d_in[17]; const float* m3be = (const float*)d_in[18];
  const float* m4w1 = (const float*)d_in[19]; const float* m4b1 = (const float*)d_in[20];
  const float* m4w2 = (const float*)d_in[21]; const float* m4b2 = (const float*)d_in[22];
  const float* m4g  = (const float*)d_in[23]; const float* m4be = (const float*)d_in[24];
  const float* wihF = (const float*)d_in[25]; const float* whhF = (const float*)d_in[26];
  const float* bihF = (const float*)d_in[27]; const float* bhhF = (const float*)d_in[28];
  const float* wihR = (const float*)d_in[29]; const float* whhR = (const float*)d_in[30];
  const float* bihR = (const float*)d_in[31]; const float* bhhR = (const float*)d_in[32];
  const float* pw   = (const float*)d_in[33]; const float* pb   = (const float*)d_in[34];
  const float* ew   = (const float*)d_in[35]; const float* eb   = (const float*)d_in[36];

  char* ws = (char*)d_ws;
  float* AUX  = (float*)(ws + 0);            // 2048 floats used
  float* ENCP = (float*)(ws + 16384);        // 4,521,984 B
  float* X    = (float*)(ws + 4538368);      // 6,291,456 B (X1 then X3)
  bf16*  E    = (bf16*)(ws + 10829824);      // 72,351,744 B (E2 then in-place E4)

  float* SUM0 = AUX + 0*128;        float* SUM1 = AUX + 1*128;
  float* SUM2 = AUX + 2*128;        float* SUM3 = AUX + 3*128;
  float* SQ0  = AUX + 512 + 0*128;  float* SQ1  = AUX + 512 + 1*128;
  float* SQ2  = AUX + 512 + 2*128;  float* SQ3  = AUX + 512 + 3*128;
  float* SC0  = AUX + 1024 + 0*128; float* SC1  = AUX + 1024 + 1*128;
  float* SC2  = AUX + 1024 + 2*128; float* SC3  = AUX + 1024 + 3*128;
  float* SH0  = AUX + 1536 + 0*128; float* SH1  = AUX + 1536 + 1*128;
  float* SH2  = AUX + 1536 + 2*128; float* SH3  = AUX + 1536 + 3*128;

  float* outP = (float*)d_out;
  float* outE = outP + PRIOR_SZ;
  float* hT   = outP + 2*PRIOR_SZ;

  k_sentinel<<<(out_size + 255)/256, 256, 0, stream>>>((const u32*)d_in[2], (float*)d_out, out_size);
  k_zero<<<1, 256, 0, stream>>>(AUX);
  k_mlp1<<<ROWS1/16, 128, 0, stream>>>(inp, m1w1, m1b1, m1w2, m1b2, X, SUM0, SQ0);
  k_bn<<<1, 128, 0, stream>>>(SUM0, SQ0, m1g, m1be, 1.f/ROWS1, SC0, SH0);
  k_mlp_edge<2*NH><<<ROWS2/8, 128, 0, stream>>>(X, SC0, SH0, nullptr, nullptr, nullptr,
                                                m2w1, m2b1, m2w2, m2b2, E, SUM1, SQ1);
  k_bn<<<1, 128, 0, stream>>>(SUM1, SQ1, m2g, m2be, 1.f/ROWS2, SC1, SH1);
  k_mlp3<<<ROWS1/16, 128, 0, stream>>>(E, SC1, SH1, m3w1, m3b1, m3w2, m3b2, X, SUM2, SQ2);
  k_bn<<<1, 128, 0, stream>>>(SUM2, SQ2, m3g, m3be, 1.f/ROWS1, SC2, SH2);
  k_mlp_edge<3*NH><<<ROWS2/8, 128, 0, stream>>>(X, SC2, SH2, E, SC1, SH1,
                                                m4w1, m4b1, m4w2, m4b2, E, SUM3, SQ3);
  k_bn<<<1, 128, 0, stream>>>(SUM3, SQ3, m4g, m4be, 1.f/ROWS2, SC3, SH3);
  k_gru_fwd<<<NSEQ/4, 256, 0, stream>>>(E, SC3, SH3, wihF, whhF, bihF, bhhF,
                                        pw, pb, ew, ENCP, outP, hT);
  k_gru_rev<<<NSEQ/4, 256, 0, stream>>>(E, SC3, SH3, wihR, whhR, bihR, bhhR,
                                        ew, eb, ENCP, outE);
}

// Round 7
// 3092.451 us; speedup vs baseline: 4.0403x; 4.0403x over previous
//
#include <hip/hip_runtime.h>
#include <hip/hip_bf16.h>
#include <cstring>

// ---- problem constants ----
#define NB 8
#define NT 64
#define NNODE 24
#define ND 6
#define NH 128
#define NR 64
#define NNE 4
#define NEDGE 552                  // NNODE*(NNODE-1)
#define NSEQ (NB*NEDGE)            // 4416
#define ROWS1 (NB*NNODE*NT)        // 12288
#define ROWS2 (NB*NEDGE*NT)        // 282624
#define PRIOR_SZ (NB*NT*NEDGE*NNE) // 1130496

typedef __hip_bfloat16 bf16;
typedef unsigned short u16;
typedef unsigned int u32;

__device__ __forceinline__ float eluf(float x){ return x > 0.f ? x : expm1f(x); }
__device__ __forceinline__ float b2f(bf16 v){ return __bfloat162float(v); }
__device__ __forceinline__ float bflo(u32 u){ return __uint_as_float(u << 16); }
__device__ __forceinline__ float bfhi(u32 u){ return __uint_as_float(u & 0xffff0000u); }
__device__ __forceinline__ u32 packbf2(float a, float b){
  bf16 ha = __float2bfloat16(a), hb = __float2bfloat16(b);
  u16 ua, ub;
  __builtin_memcpy(&ua, &ha, 2); __builtin_memcpy(&ub, &hb, 2);
  return (u32)ua | ((u32)ub << 16);
}

// ---------------- diagnostics / setup ----------------
__global__ void k_fill(float* out, int n, float pat){
  const int i = blockIdx.x*256 + threadIdx.x;
  if(i < n) out[i] = pat;
}
__global__ void k_zero(float* aux){
  for(int i = threadIdx.x; i < 1024; i += 256) aux[i] = 0.f;
}

// transpose GRU weights: wihT[k][row] = wih[row][k] (row in [0,192), k in [0,128))
//                        whhT[k][row] = whh[row][k] (k in [0,64))
__global__ void k_prep(const float* wihF, const float* whhF,
                       const float* wihR, const float* whhR,
                       float* wihTF, float* whhTF, float* wihTR, float* whhTR)
{
  const int i = blockIdx.x*256 + threadIdx.x;
  if(i < 192*128){
    const int r = i / NH, k = i - r*NH;
    wihTF[k*192 + r] = wihF[i];
    wihTR[k*192 + r] = wihR[i];
  }
  if(i < 192*64){
    const int r = i / NR, k = i - r*NR;
    whhTF[k*192 + r] = whhF[i];
    whhTR[k*192 + r] = whhR[i];
  }
}

// ---------------- MLP1: (B,N,T,D)->H->H, pre-BN out + channel sums -------------
__global__ __launch_bounds__(128) void k_mlp1(
    const float* inp, const float* w1, const float* b1,
    const float* w2, const float* b2,
    float* X1, float* sum, float* sq)
{
  const int j = threadIdx.x;
  __shared__ float xin[ND];
  __shared__ float h1[NH];
  const float b1j = b1[j], b2j = b2[j];
  float wcol[ND];
  for(int d = 0; d < ND; d++) wcol[d] = w1[d*NH + j];
  float accS = 0.f, accQ = 0.f;
  const int row0 = blockIdx.x*16;
  for(int r = 0; r < 16; r++){
    const int row = row0 + r;
    const int b = row/(NNODE*NT); const int rem = row - b*(NNODE*NT);
    const int n = rem/NT; const int t = rem - n*NT;
    if(j < ND) xin[j] = inp[((b*NT + t)*NNODE + n)*ND + j];
    __syncthreads();
    float a = b1j;
    for(int d = 0; d < ND; d++) a += xin[d]*wcol[d];
    h1[j] = eluf(a);
    __syncthreads();
    float a2 = b2j;
    for(int k = 0; k < NH; k++) a2 += h1[k]*w2[k*NH + j];
    const float h2 = eluf(a2);
    X1[row*NH + j] = h2; accS += h2; accQ += h2*h2;
    __syncthreads();
  }
  atomicAdd(&sum[j], accS); atomicAdd(&sq[j], accQ);
}

// ---------------- BN params ----------------
__global__ void k_bn(const float* sum, const float* sq,
                     const float* g, const float* be,
                     float inv_cnt, float* sc, float* sh)
{
  const int j = threadIdx.x;
  const float m = sum[j]*inv_cnt;
  const float v = fmaxf(sq[j]*inv_cnt - m*m, 0.f);
  const float s = g[j]*rsqrtf(v + 1e-5f);
  sc[j] = s; sh[j] = be[j] - m*s;
}

// ---------------- edge MLPs (MLP2: KIN=256, MLP4: KIN=384), CH=16 --------------
// LDS transposed [k][row-in-chunk] padded to 20 so [k][0..15] is 16B-aligned
// contiguous (b128 broadcast reads). For KIN=384 Eo may alias Ein (in-place):
// block stages its own 16 rows before overwriting them.
template<int KIN>
__global__ __launch_bounds__(128) void k_mlp_edge(
  const float* Xn, const float* scN, const float* shN,
  const bf16* Ein, const float* scE, const float* shE,
  const float* w1, const float* b1, const float* w2, const float* b2,
  bf16* Eo, float* sum, float* sq)
{
  const int j = threadIdx.x;
  constexpr int CH = 16, ST = 20;
  __shared__ __align__(16) float xin[KIN][ST];
  __shared__ __align__(16) float h1s[NH][ST];
  const int g0 = blockIdx.x*CH;
  // all CH rows share (b,e) since 16 | 64
  const int b = g0/(NEDGE*NT); const int rem = g0 - b*(NEDGE*NT);
  const int e = rem/NT; const int t0 = rem - e*NT;
  const int snd = e/23, r0 = e - snd*23;
  const int rcv = r0 + (r0 >= snd ? 1 : 0);
  const float sN = scN[j], tN = shN[j];
  float sE = 0.f, tE = 0.f;
  if constexpr(KIN == 3*NH){ sE = scE[j]; tE = shE[j]; }
  const int baseS = ((b*NNODE + snd)*NT + t0)*NH;
  const int baseR = ((b*NNODE + rcv)*NT + t0)*NH;
  for(int r = 0; r < CH; r++){
    xin[j][r]      = Xn[baseS + r*NH + j]*sN + tN;
    xin[NH + j][r] = Xn[baseR + r*NH + j]*sN + tN;
    if constexpr(KIN == 3*NH)
      xin[2*NH + j][r] = b2f(Ein[(size_t)(g0 + r)*NH + j])*sE + tE;
  }
  __syncthreads();
  float acc[CH];
  const float b1j = b1[j];
  #pragma unroll
  for(int r = 0; r < CH; r++) acc[r] = b1j;
  for(int k = 0; k < KIN; k++){
    const float wv = w1[k*NH + j];
    const float4 xa = *(const float4*)&xin[k][0];
    const float4 xb = *(const float4*)&xin[k][4];
    const float4 xc = *(const float4*)&xin[k][8];
    const float4 xd = *(const float4*)&xin[k][12];
    acc[0]  += xa.x*wv; acc[1]  += xa.y*wv; acc[2]  += xa.z*wv; acc[3]  += xa.w*wv;
    acc[4]  += xb.x*wv; acc[5]  += xb.y*wv; acc[6]  += xb.z*wv; acc[7]  += xb.w*wv;
    acc[8]  += xc.x*wv; acc[9]  += xc.y*wv; acc[10] += xc.z*wv; acc[11] += xc.w*wv;
    acc[12] += xd.x*wv; acc[13] += xd.y*wv; acc[14] += xd.z*wv; acc[15] += xd.w*wv;
  }
  #pragma unroll
  for(int r = 0; r < CH; r++) h1s[j][r] = eluf(acc[r]);
  __syncthreads();
  const float b2j = b2[j];
  #pragma unroll
  for(int r = 0; r < CH; r++) acc[r] = b2j;
  for(int k = 0; k < NH; k++){
    const float wv = w2[k*NH + j];
    const float4 xa = *(const float4*)&h1s[k][0];
    const float4 xb = *(const float4*)&h1s[k][4];
    const float4 xc = *(const float4*)&h1s[k][8];
    const float4 xd = *(const float4*)&h1s[k][12];
    acc[0]  += xa.x*wv; acc[1]  += xa.y*wv; acc[2]  += xa.z*wv; acc[3]  += xa.w*wv;
    acc[4]  += xb.x*wv; acc[5]  += xb.y*wv; acc[6]  += xb.z*wv; acc[7]  += xb.w*wv;
    acc[8]  += xc.x*wv; acc[9]  += xc.y*wv; acc[10] += xc.z*wv; acc[11] += xc.w*wv;
    acc[12] += xd.x*wv; acc[13] += xd.y*wv; acc[14] += xd.z*wv; acc[15] += xd.w*wv;
  }
  float accS = 0.f, accQ = 0.f;
  #pragma unroll
  for(int r = 0; r < CH; r++){
    const float h2 = eluf(acc[r]);
    Eo[(size_t)(g0 + r)*NH + j] = __float2bfloat16(h2);
    accS += h2; accQ += h2*h2;
  }
  atomicAdd(&sum[j], accS); atomicAdd(&sq[j], accQ);
}

// ---------------- agg (mean over incoming edges) + MLP3 ----------------
__global__ __launch_bounds__(128) void k_mlp3(
    const bf16* Ein, const float* scE, const float* shE,
    const float* w1, const float* b1, const float* w2, const float* b2,
    float* X3, float* sum, float* sq)
{
  const int j = threadIdx.x;
  __shared__ float xin[NH];
  __shared__ float h1[NH];
  const float sE = scE[j], tE = shE[j];
  float accS = 0.f, accQ = 0.f;
  const int row0 = blockIdx.x*16;
  for(int r = 0; r < 16; r++){
    const int row = row0 + r;
    const int b = row/(NNODE*NT); const int rem = row - b*(NNODE*NT);
    const int n = rem/NT; const int t = rem - n*NT;
    float s = 0.f;
    for(int i = 0; i < NNODE; i++){
      if(i == n) continue;
      const int e = i*23 + (n < i ? n : n - 1);
      s += b2f(Ein[((size_t)(b*NEDGE + e)*NT + t)*NH + j]);
    }
    xin[j] = sE*s*(1.f/23.f) + tE;
    __syncthreads();
    float a = b1[j];
    for(int k = 0; k < NH; k++) a += xin[k]*w1[k*NH + j];
    h1[j] = eluf(a);
    __syncthreads();
    float a2 = b2[j];
    for(int k = 0; k < NH; k++) a2 += h1[k]*w2[k*NH + j];
    const float h2 = eluf(a2);
    X3[row*NH + j] = h2; accS += h2; accQ += h2*h2;
    __syncthreads();
  }
  atomicAdd(&sum[j], accS); atomicAdd(&sq[j], accQ);
}

// ---------------- GRU: both directions, 1 wave per sequence -------------------
// Phase 1: xw[t][g*64+c] = (x_t @ wihT + bih) into LDS bf16, via transposed
//          coalesced weights and b128 LDS x-broadcasts.
// Phase 2: recurrence with whhT packed bf16x2 in registers; h fp32 in LDS.
__global__ __launch_bounds__(64, 1) void k_gru(
  const bf16* E4, const float* sc4, const float* sh4,
  const float* wihTF, const float* whhTF, const float* bihF, const float* bhhF,
  const float* wihTR, const float* whhTR, const float* bihR, const float* bhhR,
  const float* pw, const float* pb, const float* ew,
  bf16* encpF, bf16* encpR, float* outP, float* hT)
{
  __shared__ __align__(16) bf16 xw[NT][192];      // 24576 B
  __shared__ __align__(16) bf16 xst[NH][16];      // 4096 B
  __shared__ __align__(16) float hs[NR];          // 256 B
  const int c = threadIdx.x;
  const int bid = blockIdx.x;
  const int dir = (bid >= NSEQ) ? 1 : 0;
  const int s = dir ? (bid - NSEQ) : bid;
  const int sb = s / NEDGE, se = s - sb*NEDGE;
  const float* wihT = dir ? wihTR : wihTF;
  const float* whhT = dir ? whhTR : whhTF;
  const float* bih  = dir ? bihR  : bihF;
  const float* bhh  = dir ? bhhR  : bhhF;
  const float bxr = bih[c], bxz = bih[64+c], bxn = bih[128+c];
  const float bhr = bhh[c], bhz = bhh[64+c], bhn = bhh[128+c];
  const float sc_a = sc4[c], sc_b = sc4[c+64];
  const float sh_a = sh4[c], sh_b = sh4[c+64];

  // ---- phase 1: x-projection into LDS ----
  for(int t0 = 0; t0 < NT; t0 += 16){
    for(int tp = 0; tp < 16; tp++){
      const size_t xb = ((size_t)s*NT + t0 + tp)*NH;
      xst[c][tp]      = __float2bfloat16(b2f(E4[xb + c])*sc_a + sh_a);
      xst[c + 64][tp] = __float2bfloat16(b2f(E4[xb + c + 64])*sc_b + sh_b);
    }
    __syncthreads();
    float ar[16], az[16], an[16];
    #pragma unroll
    for(int tp = 0; tp < 16; tp++){ ar[tp] = bxr; az[tp] = bxz; an[tp] = bxn; }
    #pragma unroll 2
    for(int k = 0; k < NH; k++){
      const float wr = wihT[k*192 + c];
      const float wz = wihT[k*192 + 64 + c];
      const float wn = wihT[k*192 + 128 + c];
      const uint4 q0 = *(const uint4*)&xst[k][0];
      const uint4 q1 = *(const uint4*)&xst[k][8];
      float xv[16];
      xv[0]=bflo(q0.x); xv[1]=bfhi(q0.x); xv[2]=bflo(q0.y); xv[3]=bfhi(q0.y);
      xv[4]=bflo(q0.z); xv[5]=bfhi(q0.z); xv[6]=bflo(q0.w); xv[7]=bfhi(q0.w);
      xv[8]=bflo(q1.x); xv[9]=bfhi(q1.x); xv[10]=bflo(q1.y); xv[11]=bfhi(q1.y);
      xv[12]=bflo(q1.z); xv[13]=bfhi(q1.z); xv[14]=bflo(q1.w); xv[15]=bfhi(q1.w);
      #pragma unroll
      for(int tp = 0; tp < 16; tp++){
        ar[tp] += xv[tp]*wr; az[tp] += xv[tp]*wz; an[tp] += xv[tp]*wn;
      }
    }
    #pragma unroll
    for(int tp = 0; tp < 16; tp++){
      xw[t0+tp][c]        = __float2bfloat16(ar[tp]);
      xw[t0+tp][64 + c]   = __float2bfloat16(az[tp]);
      xw[t0+tp][128 + c]  = __float2bfloat16(an[tp]);
    }
    __syncthreads();
  }

  // ---- load whhT into registers (bf16x2 packed, 96 VGPRs) ----
  u32 wr2[32], wz2[32], wn2[32];
  #pragma unroll
  for(int kk = 0; kk < 32; kk++){
    wr2[kk] = packbf2(whhT[(2*kk)*192 + c],        whhT[(2*kk+1)*192 + c]);
    wz2[kk] = packbf2(whhT[(2*kk)*192 + 64 + c],   whhT[(2*kk+1)*192 + 64 + c]);
    wn2[kk] = packbf2(whhT[(2*kk)*192 + 128 + c],  whhT[(2*kk+1)*192 + 128 + c]);
  }

  float pwl[NNE], ewl[NNE];
  #pragma unroll
  for(int l = 0; l < NNE; l++){
    pwl[l] = dir ? 0.f : pw[c*NNE + l];
    ewl[l] = dir ? ew[(NR + c)*NNE + l] : ew[c*NNE + l];
  }
  const float pbl = (c < NNE) ? pb[c] : 0.f;

  // ---- phase 2: recurrence ----
  hs[c] = 0.f;
  float hprev = 0.f;
  __syncthreads();
  for(int i2 = 0; i2 < NT; i2++){
    const int t = dir ? (NT - 1 - i2) : i2;
    float xr = b2f(xw[t][c]), xz = b2f(xw[t][64 + c]), xn = b2f(xw[t][128 + c]);
    float hr = bhr, hz = bhz, hn = bhn;
    #pragma unroll
    for(int kk = 0; kk < 32; kk++){
      const float2 hp = *(const float2*)&hs[2*kk];
      const u32 ur = wr2[kk], uz = wz2[kk], un = wn2[kk];
      hr += hp.x*bflo(ur) + hp.y*bfhi(ur);
      hz += hp.x*bflo(uz) + hp.y*bfhi(uz);
      hn += hp.x*bflo(un) + hp.y*bfhi(un);
    }
    const float rg = 1.f/(1.f + expf(-(xr + hr)));
    const float zg = 1.f/(1.f + expf(-(xz + hz)));
    const float ng = tanhf(xn + rg*hn);
    const float hnew = (1.f - zg)*ng + zg*hprev;
    __syncthreads();
    hs[c] = hnew; hprev = hnew;
    __syncthreads();
    if(!dir){
      float v[8];
      #pragma unroll
      for(int l = 0; l < NNE; l++){ v[l] = hnew*pwl[l]; v[4+l] = hnew*ewl[l]; }
      #pragma unroll
      for(int m = 1; m < 64; m <<= 1){
        #pragma unroll
        for(int q = 0; q < 8; q++) v[q] += __shfl_xor(v[q], m);
      }
      const float pv = (c&2) ? ((c&1)?v[3]:v[2]) : ((c&1)?v[1]:v[0]);
      const float ev = (c&2) ? ((c&1)?v[7]:v[6]) : ((c&1)?v[5]:v[4]);
      if(c < NNE){
        outP[(((size_t)(sb*NT + t))*NEDGE + se)*NNE + c] = pv + pbl;
      } else if(c < 2*NNE){
        encpF[((size_t)s*NT + t)*NNE + (c - NNE)] = __float2bfloat16(ev);
      }
    } else {
      float v[NNE];
      #pragma unroll
      for(int l = 0; l < NNE; l++) v[l] = hnew*ewl[l];
      #pragma unroll
      for(int m = 1; m < 64; m <<= 1){
        #pragma unroll
        for(int q = 0; q < NNE; q++) v[q] += __shfl_xor(v[q], m);
      }
      const float ev = (c&2) ? ((c&1)?v[3]:v[2]) : ((c&1)?v[1]:v[0]);
      if(c < NNE){
        encpR[((size_t)s*NT + t)*NNE + c] = __float2bfloat16(ev);
      }
    }
  }
  if(!dir) hT[(size_t)s*NR + c] = hprev;
}

// ---------------- merge enc halves + bias ----------------
__global__ void k_add(const bf16* eF, const bf16* eR, const float* eb, float* outE){
  const int i = blockIdx.x*256 + threadIdx.x;
  if(i >= PRIOR_SZ) return;
  const int l = i & 3; const int r2 = i >> 2;
  const int e = r2 % NEDGE; const int r3 = r2 / NEDGE;
  const int t = r3 % NT; const int b = r3 / NT;
  const int s = b*NEDGE + e;
  const size_t src = ((size_t)s*NT + t)*NNE + l;
  outE[i] = b2f(eF[src]) + b2f(eR[src]) + eb[l];
}

extern "C" void kernel_launch(void* const* d_in, const int* in_sizes, int n_in,
                              void* d_out, int out_size, void* d_ws, size_t ws_size,
                              hipStream_t stream)
{
  const size_t NEED = 78659584ull;
  if(ws_size < NEED){
    k_fill<<<(out_size + 255)/256, 256, 0, stream>>>((float*)d_out, out_size, 3584.0f);
    return;
  }
  const float* inp  = (const float*)d_in[0];
  const float* m1w1 = (const float*)d_in[1];  const float* m1b1 = (const float*)d_in[2];
  const float* m1w2 = (const float*)d_in[3];  const float* m1b2 = (const float*)d_in[4];
  const float* m1g  = (const float*)d_in[5];  const float* m1be = (const float*)d_in[6];
  const float* m2w1 = (const float*)d_in[7];  const float* m2b1 = (const float*)d_in[8];
  const float* m2w2 = (const float*)d_in[9];  const float* m2b2 = (const float*)d_in[10];
  const float* m2g  = (const float*)d_in[11]; const float* m2be = (const float*)d_in[12];
  const float* m3w1 = (const float*)d_in[13]; const float* m3b1 = (const float*)d_in[14];
  const float* m3w2 = (const float*)d_in[15]; const float* m3b2 = (const float*)d_in[16];
  const float* m3g  = (const float*)d_in[17]; const float* m3be = (const float*)d_in[18];
  const float* m4w1 = (const float*)d_in[19]; const float* m4b1 = (const float*)d_in[20];
  const float* m4w2 = (const float*)d_in[21]; const float* m4b2 = (const float*)d_in[22];
  const float* m4g  = (const float*)d_in[23]; const float* m4be = (const float*)d_in[24];
  const float* wihF = (const float*)d_in[25]; const float* whhF = (const float*)d_in[26];
  const float* bihF = (const float*)d_in[27]; const float* bhhF = (const float*)d_in[28];
  const float* wihR = (const float*)d_in[29]; const float* whhR = (const float*)d_in[30];
  const float* bihR = (const float*)d_in[31]; const float* bhhR = (const float*)d_in[32];
  const float* pw   = (const float*)d_in[33]; const float* pb   = (const float*)d_in[34];
  const float* ew   = (const float*)d_in[35]; const float* eb   = (const float*)d_in[36];

  char* ws = (char*)d_ws;
  float* AUX = (float*)(ws + 0);             // 16 KB reserved
  char*  Xr  = ws + 16384;                   // 6,291,456 B (X1 then X3)
  float* X   = (float*)Xr;
  bf16*  E   = (bf16*)(ws + 16384 + 6291456); // 72,351,744 B (E2 then in-place E4)
  // aliases inside X region, valid AFTER mlp4 has consumed X3:
  float* wihTF = (float*)(Xr + 0);           // 98,304 B
  float* wihTR = (float*)(Xr + 98304);       // 98,304 B
  float* whhTF = (float*)(Xr + 196608);      // 49,152 B
  float* whhTR = (float*)(Xr + 245760);      // 49,152 B -> 294,912
  bf16*  encpF = (bf16*)(Xr + 294912);       // 2,260,992 B
  bf16*  encpR = (bf16*)(Xr + 2555904);      // 2,260,992 B -> 4,816,896 <= 6,291,456

  float* SUM0 = AUX + 0*128;        float* SUM1 = AUX + 1*128;
  float* SUM2 = AUX + 2*128;        float* SUM3 = AUX + 3*128;
  float* SQ0  = AUX + 512 + 0*128;  float* SQ1  = AUX + 512 + 1*128;
  float* SQ2  = AUX + 512 + 2*128;  float* SQ3  = AUX + 512 + 3*128;
  float* SC0  = AUX + 1024 + 0*128; float* SC1  = AUX + 1024 + 1*128;
  float* SC2  = AUX + 1024 + 2*128; float* SC3  = AUX + 1024 + 3*128;
  float* SH0  = AUX + 1536 + 0*128; float* SH1  = AUX + 1536 + 1*128;
  float* SH2  = AUX + 1536 + 2*128; float* SH3  = AUX + 1536 + 3*128;

  float* outP = (float*)d_out;
  float* outE = outP + PRIOR_SZ;
  float* hT   = outP + 2*PRIOR_SZ;

  k_zero<<<1, 256, 0, stream>>>(AUX);
  k_mlp1<<<ROWS1/16, 128, 0, stream>>>(inp, m1w1, m1b1, m1w2, m1b2, X, SUM0, SQ0);
  k_bn<<<1, 128, 0, stream>>>(SUM0, SQ0, m1g, m1be, 1.f/ROWS1, SC0, SH0);
  k_mlp_edge<2*NH><<<ROWS2/16, 128, 0, stream>>>(X, SC0, SH0, nullptr, nullptr, nullptr,
                                                 m2w1, m2b1, m2w2, m2b2, E, SUM1, SQ1);
  k_bn<<<1, 128, 0, stream>>>(SUM1, SQ1, m2g, m2be, 1.f/ROWS2, SC1, SH1);
  k_mlp3<<<ROWS1/16, 128, 0, stream>>>(E, SC1, SH1, m3w1, m3b1, m3w2, m3b2, X, SUM2, SQ2);
  k_bn<<<1, 128, 0, stream>>>(SUM2, SQ2, m3g, m3be, 1.f/ROWS1, SC2, SH2);
  k_mlp_edge<3*NH><<<ROWS2/16, 128, 0, stream>>>(X, SC2, SH2, E, SC1, SH1,
                                                 m4w1, m4b1, m4w2, m4b2, E, SUM3, SQ3);
  k_bn<<<1, 128, 0, stream>>>(SUM3, SQ3, m4g, m4be, 1.f/ROWS2, SC3, SH3);
  // X region is now dead -> transpose GRU weights into it
  k_prep<<<96, 256, 0, stream>>>(wihF, whhF, wihR, whhR, wihTF, whhTF, wihTR, whhTR);
  k_gru<<<2*NSEQ, 64, 0, stream>>>(E, SC3, SH3,
                                   wihTF, whhTF, bihF, bhhF,
                                   wihTR, whhTR, bihR, bhhR,
                                   pw, pb, ew, encpF, encpR, outP, hT);
  k_add<<<(PRIOR_SZ + 255)/256, 256, 0, stream>>>(encpF, encpR, eb, outE);
}